// Round 2
// baseline (1520.426 us; speedup 1.0000x reference)
//
#include <hip/hip_runtime.h>
#include <hip/hip_bf16.h>
#include <stdint.h>

#define NN 4096
#define DD 256
#define NL 3
typedef unsigned int uint;
typedef unsigned short ushort_t;

typedef float f32x4 __attribute__((ext_vector_type(4)));
typedef short bf16x8 __attribute__((ext_vector_type(8)));

struct Ptrs4 { const float* p0; const float* p1; const float* p2; const float* p3; };
__device__ __forceinline__ const float* sel(const Ptrs4& p, int b) {
    return b == 0 ? p.p0 : b == 1 ? p.p1 : b == 2 ? p.p2 : p.p3;
}

// packed bf16 pair (RNE), low half = a, high half = b
__device__ __forceinline__ uint pkbf2(float a, float b) {
    __hip_bfloat162 t = __float22bfloat162_rn(float2{a, b});
    union { __hip_bfloat162 h; uint u; } c; c.h = t; return c.u;
}
// exact 3-way split of a pair: x = h + m + l + r, |r| <= ~2^-27 |x|
__device__ __forceinline__ void split3_pk(float a, float b, uint& h, uint& m, uint& l) {
    h = pkbf2(a, b);
    float ha = __uint_as_float(h << 16), hb = __uint_as_float(h & 0xFFFF0000u);
    float ra = a - ha, rb = b - hb;
    m = pkbf2(ra, rb);
    float ma = __uint_as_float(m << 16), mb = __uint_as_float(m & 0xFFFF0000u);
    l = pkbf2(ra - ma, rb - mb);
}

// async global->LDS, 16B per lane; LDS dest = wave-uniform base + lane*16
typedef __attribute__((address_space(3))) uint lds_u32;
typedef __attribute__((address_space(1))) const uint glb_u32;
__device__ __forceinline__ void gload16(void* l, const void* g) {
    __builtin_amdgcn_global_load_lds((glb_u32*)g, (lds_u32*)l, 16, 0, 0);
}

// ---------------------------------------------------------------------------
// fp32 GEMM (proven): Out = act(X @ W + b).
// MODE 0: elu; MODE 1: elu + colsum (fp32 out, fallback path);
// MODE 2: linear + BN stats;
// MODE 3: elu + colsum, output = bf16 3-split in Hs[lvl][k/8][n][8] layout
//         (no fp32 out) -- feeds adj_mfma_v2 directly.
// ---------------------------------------------------------------------------
template<int MODE>
__global__ __launch_bounds__(256, 4)
void gemm_small(const float* __restrict__ Xin, Ptrs4 Wp, Ptrs4 bp,
                float* __restrict__ Out, float* __restrict__ cs, float* __restrict__ csq,
                ushort_t* __restrict__ Hso)
{
    const int b = blockIdx.z;
    const float* Wb = sel(Wp, b);
    const float* bb = sel(bp, b);
    const float* X = Xin + (size_t)b * NN * DD;
    float* O = Out + (size_t)b * NN * DD;
    ushort_t* HsO = Hso + (size_t)b * 3 * (size_t)DD * NN;
    const int row0 = blockIdx.y * 128, col0 = blockIdx.x * 64;
    const int tid = threadIdx.x;
    __shared__ float Asm[16][132];
    __shared__ float Bsm[16][68];
    const int tr = (tid >> 4) << 3, tc = (tid & 15) << 2;
    const int m = tid & 127, kk = (tid >> 7) << 3;
    float acc[8][4] = {};
    for (int k0 = 0; k0 < DD; k0 += 16) {
        {
            const float* s1 = X + (size_t)(row0 + m) * DD + k0 + kk;
            float4 v0 = *(const float4*)s1, v1 = *(const float4*)(s1 + 4);
            Asm[kk+0][m]=v0.x; Asm[kk+1][m]=v0.y; Asm[kk+2][m]=v0.z; Asm[kk+3][m]=v0.w;
            Asm[kk+4][m]=v1.x; Asm[kk+5][m]=v1.y; Asm[kk+6][m]=v1.z; Asm[kk+7][m]=v1.w;
        }
        {
            const int k = tid >> 4, n = (tid & 15) << 2;
            *(float4*)&Bsm[k][n] = *(const float4*)(Wb + (size_t)(k0 + k) * DD + col0 + n);
        }
        __syncthreads();
        #pragma unroll
        for (int k = 0; k < 16; ++k) {
            float a[8], bv[4];
            *(float4*)&a[0] = *(const float4*)&Asm[k][tr];
            *(float4*)&a[4] = *(const float4*)&Asm[k][tr + 4];
            *(float4*)&bv[0] = *(const float4*)&Bsm[k][tc];
            #pragma unroll
            for (int i = 0; i < 8; ++i)
                #pragma unroll
                for (int j = 0; j < 4; ++j)
                    acc[i][j] = fmaf(a[i], bv[j], acc[i][j]);
        }
        __syncthreads();
    }
    float bias4[4];
    *(float4*)bias4 = *(const float4*)(bb + col0 + tc);
    float s4[4] = {0.f,0.f,0.f,0.f}, q4[4] = {0.f,0.f,0.f,0.f};
    // MODE 3 split-store geometry: d = col0+tc (mult of 4), layout [lvl][d>>3][n][8]
    const int dph = col0 + tc;
    const size_t sb3 = (size_t)(dph >> 3) * (NN * 8) + (dph & 4);
    #pragma unroll
    for (int i = 0; i < 8; ++i) {
        float ov[4];
        #pragma unroll
        for (int j = 0; j < 4; ++j) {
            float v = acc[i][j] + bias4[j];
            if (MODE == 0 || MODE == 1 || MODE == 3) v = (v > 0.f) ? v : (expf(v) - 1.f);
            ov[j] = v;
            if (MODE == 1 || MODE == 3) s4[j] += v;
            if (MODE == 2) { s4[j] += v; q4[j] += v * v; }
        }
        if (MODE == 3) {
            uint2 vh, vm, vl;
            split3_pk(ov[0], ov[1], vh.x, vm.x, vl.x);
            split3_pk(ov[2], ov[3], vh.y, vm.y, vl.y);
            size_t off = sb3 + (size_t)(row0 + tr + i) * 8;
            *(uint2*)(HsO + off) = vh;
            *(uint2*)(HsO + (size_t)DD * NN + off) = vm;
            *(uint2*)(HsO + (size_t)2 * DD * NN + off) = vl;
        } else {
            float4 o; o.x = ov[0]; o.y = ov[1]; o.z = ov[2]; o.w = ov[3];
            *(float4*)(O + (size_t)(row0 + tr + i) * DD + col0 + tc) = o;
        }
    }
    if (MODE == 1 || MODE == 2 || MODE == 3) {
        __syncthreads();
        const int rg = tid >> 4;
        #pragma unroll
        for (int j = 0; j < 4; ++j) {
            Asm[rg][tc + j] = s4[j];
            if (MODE == 2) Bsm[rg][tc + j] = q4[j];
        }
        __syncthreads();
        if (tid < 64) {
            float s = 0.f, q = 0.f;
            #pragma unroll
            for (int r = 0; r < 16; ++r) { s += Asm[r][tid]; if (MODE == 2) q += Bsm[r][tid]; }
            atomicAdd(&cs[b * DD + col0 + tid], s);
            if (MODE == 2) atomicAdd(&csq[b * DD + col0 + tid], q);
        }
    }
}

// threshold per branch: t = ||colsum||^2 / N^2
__global__ void thresh_k(const float* __restrict__ cs, float* __restrict__ tvals)
{
    const int b = blockIdx.x, t = threadIdx.x;
    __shared__ float red[256];
    float v = cs[b * DD + t];
    red[t] = v * v;
    __syncthreads();
    for (int s = 128; s > 0; s >>= 1) { if (t < s) red[t] += red[t + s]; __syncthreads(); }
    if (t == 0) tvals[b] = red[0] * (1.0f / 16777216.0f);
}

// ---------------------------------------------------------------------------
// transpose + exact 3-split: X[b][n][d] fp32 -> S{h,m,l}[b][d][j=n] bf16.
// j-contiguous layout = MFMA k-order for masked_mfma's B operand.  (proven)
// ---------------------------------------------------------------------------
__global__ __launch_bounds__(256)
void tsplit_x(const float* __restrict__ Xin, ushort_t* __restrict__ Sh,
              ushort_t* __restrict__ Sm, ushort_t* __restrict__ Sl)
{
    const int b = blockIdx.z;
    const int n0 = blockIdx.x * 64, d0 = blockIdx.y * 64;
    const float* X = Xin + (size_t)b * NN * DD;
    __shared__ float ls[64][65];
    const int tid = threadIdx.x;
    #pragma unroll
    for (int i = 0; i < 4; ++i) {
        int u = (i << 8) + tid;
        int r = u >> 4, c4 = (u & 15) << 2;   // r = n-row, c4 = d offset
        float4 v = *(const float4*)(X + (size_t)(n0 + r) * DD + d0 + c4);
        ls[r][c4] = v.x; ls[r][c4+1] = v.y; ls[r][c4+2] = v.z; ls[r][c4+3] = v.w;
    }
    __syncthreads();
    const int d = tid >> 2, seg = (tid & 3) << 4;   // 16 n-values per thread
    uint ph[8], pm[8], pl[8];
    #pragma unroll
    for (int jj = 0; jj < 8; ++jj) {
        float a = ls[seg + 2 * jj][d];
        float c = ls[seg + 2 * jj + 1][d];
        split3_pk(a, c, ph[jj], pm[jj], pl[jj]);
    }
    size_t idx = ((size_t)(b * DD + d0 + d)) * NN + n0 + seg;   // ushort units
    *(uint4*)(Sh + idx)     = *(uint4*)&ph[0];
    *(uint4*)(Sh + idx + 8) = *(uint4*)&ph[4];
    *(uint4*)(Sm + idx)     = *(uint4*)&pm[0];
    *(uint4*)(Sm + idx + 8) = *(uint4*)&pm[4];
    *(uint4*)(Sl + idx)     = *(uint4*)&pl[0];
    *(uint4*)(Sl + idx + 8) = *(uint4*)&pl[4];
}

// ---------------------------------------------------------------------------
// adj v1 (fallback, proven): fp32 staging + in-tile split.
// ---------------------------------------------------------------------------
__global__ __launch_bounds__(256, 3)
void adj_mfma_s(const float* __restrict__ H, const float* __restrict__ tvals,
                uint8_t* __restrict__ mask)
{
    int t = blockIdx.x;
    int by = 0, rem = 32;
    while (t >= rem) { t -= rem; rem--; by++; }
    const int bx = by + t;
    const int b = blockIdx.z;
    const int row0 = by * 128, col0 = bx * 128;
    const int tid = threadIdx.x;
    const int wave = tid >> 6, ln = tid & 15, quad = (tid >> 4) & 3;
    const int wrow = wave >> 1, wcol = wave & 1;
    const float* Hb = H + (size_t)b * NN * DD;
    uint8_t* Mb = mask + (size_t)b * NN * (NN / 8);
    __shared__ ushort_t hs[2][3][128][34];   // [side][lvl][row][32k+pad], 51.0 KB

    f32x4 acc[4][4] = {};
    for (int k0 = 0; k0 < DD; k0 += 32) {
        #pragma unroll
        for (int i = 0; i < 8; ++i) {
            int f = (i << 8) + tid;
            int sr = f >> 3;
            int side = sr >> 7, r = sr & 127, part = f & 7;
            int grow = (side ? col0 : row0) + r;
            float4 v = *(const float4*)(Hb + (size_t)grow * DD + k0 + part * 4);
            uint h0, m0, l0, h1, m1, l1;
            split3_pk(v.x, v.y, h0, m0, l0);
            split3_pk(v.z, v.w, h1, m1, l1);
            uint2 ph; ph.x = h0; ph.y = h1;
            uint2 pm; pm.x = m0; pm.y = m1;
            uint2 pl; pl.x = l0; pl.y = l1;
            *(uint2*)&hs[side][0][r][part * 4] = ph;
            *(uint2*)&hs[side][1][r][part * 4] = pm;
            *(uint2*)&hs[side][2][r][part * 4] = pl;
        }
        __syncthreads();
        bf16x8 af[4][3];
        #pragma unroll
        for (int mt = 0; mt < 4; ++mt)
            #pragma unroll
            for (int lvl = 0; lvl < 3; ++lvl)
                af[mt][lvl] = *(const bf16x8*)&hs[0][lvl][wrow * 64 + mt * 16 + ln][quad * 8];
        #pragma unroll
        for (int nt = 0; nt < 4; ++nt) {
            int n = wcol * 64 + nt * 16 + ln;
            bf16x8 bh = *(const bf16x8*)&hs[1][0][n][quad * 8];
            bf16x8 bm = *(const bf16x8*)&hs[1][1][n][quad * 8];
            bf16x8 bl = *(const bf16x8*)&hs[1][2][n][quad * 8];
            #pragma unroll
            for (int mt = 0; mt < 4; ++mt) {
                f32x4 a = acc[mt][nt];
                a = __builtin_amdgcn_mfma_f32_16x16x32_bf16(af[mt][0], bh, a, 0, 0, 0);
                a = __builtin_amdgcn_mfma_f32_16x16x32_bf16(af[mt][0], bm, a, 0, 0, 0);
                a = __builtin_amdgcn_mfma_f32_16x16x32_bf16(af[mt][1], bh, a, 0, 0, 0);
                a = __builtin_amdgcn_mfma_f32_16x16x32_bf16(af[mt][0], bl, a, 0, 0, 0);
                a = __builtin_amdgcn_mfma_f32_16x16x32_bf16(af[mt][2], bh, a, 0, 0, 0);
                a = __builtin_amdgcn_mfma_f32_16x16x32_bf16(af[mt][1], bm, a, 0, 0, 0);
                acc[mt][nt] = a;
            }
        }
        __syncthreads();
    }
    const float t2 = tvals[b];
    #pragma unroll
    for (int mt = 0; mt < 4; ++mt)
        #pragma unroll
        for (int nt = 0; nt < 4; ++nt) {
            bool p0 = acc[mt][nt][0] > t2, p1 = acc[mt][nt][1] > t2;
            bool p2 = acc[mt][nt][2] > t2, p3 = acc[mt][nt][3] > t2;
            unsigned long long bal[4];
            bal[0] = __ballot(p0); bal[1] = __ballot(p1);
            bal[2] = __ballot(p2); bal[3] = __ballot(p3);
            if ((tid & 63) < 16) {
                int q = ln >> 2, rsel = ln & 3;
                unsigned long long bv = rsel == 0 ? bal[0] : rsel == 1 ? bal[1]
                                       : rsel == 2 ? bal[2] : bal[3];
                ushort_t u16 = (ushort_t)((bv >> (q * 16)) & 0xFFFFull);
                int row = row0 + wrow * 64 + mt * 16 + ln;
                int colb = (col0 + wcol * 64 + nt * 16) >> 3;
                *(ushort_t*)(Mb + (size_t)row * (NN / 8) + colb) = u16;
            }
            uint nib = (p0 ? 1u : 0u) | (p1 ? 2u : 0u) | (p2 ? 4u : 0u) | (p3 ? 8u : 0u);
            uint other = (uint)__shfl_xor((int)nib, 16);
            if ((quad & 1) == 0) {
                uint byt = nib | (other << 4);
                int rowm = col0 + wcol * 64 + nt * 16 + ln;
                int colbm = ((row0 + wrow * 64 + mt * 16) >> 3) + (quad >> 1);
                Mb[(size_t)rowm * (NN / 8) + colbm] = (uint8_t)byt;
            }
        }
}

// ---------------------------------------------------------------------------
// adj v2 (fast path): pure bf16 MFMA from precomputed splits. (proven R0)
// ---------------------------------------------------------------------------
__global__ __launch_bounds__(256, 3)
void adj_mfma_v2(const ushort_t* __restrict__ Hs, const float* __restrict__ tvals,
                 uint8_t* __restrict__ mask)
{
    int t = blockIdx.x;
    int by = 0, rem = 32;
    while (t >= rem) { t -= rem; rem--; by++; }
    const int bx = by + t;
    const int b = blockIdx.z;
    const int row0 = by * 128, col0 = bx * 128;
    const int tid = threadIdx.x;
    const int wave = tid >> 6, ln = tid & 15, quad = (tid >> 4) & 3;
    const int wrow = wave >> 1, wcol = wave & 1;
    const ushort_t* Hb = Hs + (size_t)b * 3 * (size_t)DD * NN;
    uint8_t* Mb = mask + (size_t)b * NN * (NN / 8);
    __shared__ ushort_t hs2[6][4][128][8];   // 48 KB, linear (DMA-friendly)

    const int grow = tid & 127;
    const int qb = tid >> 7;                  // 0/1
    const size_t var0 = (size_t)qb * (NN * 8) + (size_t)(row0 + grow) * 8;
    const size_t var1 = (size_t)qb * (NN * 8) + (size_t)(col0 + grow) * 8;

    f32x4 acc[4][4] = {};
    for (int kb0 = 0; kb0 < DD / 8; kb0 += 4) {     // 32 k per iter
        #pragma unroll
        for (int c = 0; c < 12; ++c) {
            const int sl = c >> 1, part = c & 1;    // sl = side*3+lvl
            const int side = sl / 3, lvl = sl % 3;
            const ushort_t* g = Hb + (size_t)lvl * DD * NN
                                   + (size_t)(kb0 + part * 2) * (NN * 8)
                                   + (side ? var1 : var0);
            char* l = (char*)&hs2[0][0][0][0] + (((sl * 8 + part * 4 + wave)) << 10);
            gload16(l, g);
        }
        __syncthreads();
        bf16x8 af[4][3];
        #pragma unroll
        for (int mt = 0; mt < 4; ++mt)
            #pragma unroll
            for (int lvl = 0; lvl < 3; ++lvl)
                af[mt][lvl] = *(const bf16x8*)&hs2[lvl][quad][wrow * 64 + mt * 16 + ln][0];
        #pragma unroll
        for (int nt = 0; nt < 4; ++nt) {
            const int n = wcol * 64 + nt * 16 + ln;
            bf16x8 bh = *(const bf16x8*)&hs2[3][quad][n][0];
            bf16x8 bm = *(const bf16x8*)&hs2[4][quad][n][0];
            bf16x8 bl = *(const bf16x8*)&hs2[5][quad][n][0];
            #pragma unroll
            for (int mt = 0; mt < 4; ++mt) {
                f32x4 a = acc[mt][nt];
                a = __builtin_amdgcn_mfma_f32_16x16x32_bf16(af[mt][0], bh, a, 0, 0, 0);
                a = __builtin_amdgcn_mfma_f32_16x16x32_bf16(af[mt][0], bm, a, 0, 0, 0);
                a = __builtin_amdgcn_mfma_f32_16x16x32_bf16(af[mt][1], bh, a, 0, 0, 0);
                a = __builtin_amdgcn_mfma_f32_16x16x32_bf16(af[mt][0], bl, a, 0, 0, 0);
                a = __builtin_amdgcn_mfma_f32_16x16x32_bf16(af[mt][2], bh, a, 0, 0, 0);
                a = __builtin_amdgcn_mfma_f32_16x16x32_bf16(af[mt][1], bm, a, 0, 0, 0);
                acc[mt][nt] = a;
            }
        }
        __syncthreads();
    }
    const float t2 = tvals[b];
    #pragma unroll
    for (int mt = 0; mt < 4; ++mt)
        #pragma unroll
        for (int nt = 0; nt < 4; ++nt) {
            bool p0 = acc[mt][nt][0] > t2, p1 = acc[mt][nt][1] > t2;
            bool p2 = acc[mt][nt][2] > t2, p3 = acc[mt][nt][3] > t2;
            unsigned long long bal[4];
            bal[0] = __ballot(p0); bal[1] = __ballot(p1);
            bal[2] = __ballot(p2); bal[3] = __ballot(p3);
            if ((tid & 63) < 16) {
                int q = ln >> 2, rsel = ln & 3;
                unsigned long long bv = rsel == 0 ? bal[0] : rsel == 1 ? bal[1]
                                       : rsel == 2 ? bal[2] : bal[3];
                ushort_t u16 = (ushort_t)((bv >> (q * 16)) & 0xFFFFull);
                int row = row0 + wrow * 64 + mt * 16 + ln;
                int colb = (col0 + wcol * 64 + nt * 16) >> 3;
                *(ushort_t*)(Mb + (size_t)row * (NN / 8) + colb) = u16;
            }
            uint nib = (p0 ? 1u : 0u) | (p1 ? 2u : 0u) | (p2 ? 4u : 0u) | (p3 ? 8u : 0u);
            uint other = (uint)__shfl_xor((int)nib, 16);
            if ((quad & 1) == 0) {
                uint byt = nib | (other << 4);
                int rowm = col0 + wcol * 64 + nt * 16 + ln;
                int colbm = ((row0 + wrow * 64 + mt * 16) >> 3) + (quad >> 1);
                Mb[(size_t)rowm * (NN / 8) + colbm] = (uint8_t)byt;
            }
        }
}

// ---------------------------------------------------------------------------
// X' = X + M @ X via MFMA, IN-PLACE into X.
// R11: T14 async-STAGE software pipeline (bit-exact): issue next-tile global
// loads into regs BEFORE the MFMA phase; vmcnt-wait + ds_write after the
// barrier. Hides ~L2 latency under the 24-MFMA cluster at 2 blocks/CU.
// ---------------------------------------------------------------------------
__global__ __launch_bounds__(256, 6)
void masked_mfma(float* __restrict__ Xio, const ushort_t* __restrict__ Sh,
                 const ushort_t* __restrict__ Sm, const ushort_t* __restrict__ Sl,
                 const uint8_t* __restrict__ mask)
{
    const int b = blockIdx.z;
    const int row0 = blockIdx.y * 128, col0 = blockIdx.x * 64;
    const int tid = threadIdx.x;
    const int wave = tid >> 6, ln = tid & 15, quad = (tid >> 4) & 3;
    const int wrow = wave >> 1, wcol = wave & 1;
    float* X = Xio + (size_t)b * NN * DD;
    const size_t sb = (size_t)b * DD * NN;
    const ushort_t* Ss[3] = { Sh + sb, Sm + sb, Sl + sb };
    const uint* Mw = (const uint*)(mask + (size_t)b * NN * (NN / 8));
    __shared__ ushort_t bt[3][64][40];
    __shared__ uint msk[128];

    f32x4 acc[4][2] = {};
    const int scol = tid >> 2, spart = tid & 3;
    const size_t scoff = (size_t)(col0 + scol) * NN + spart * 8;   // ushort units
    const size_t moff = (size_t)(row0 + (tid & 127)) * 128;        // uint units

    uint4 pf0, pf1, pf2; uint pfm;
    // prologue: tile 0 -> regs -> LDS
    pf0 = *(const uint4*)(Ss[0] + scoff);
    pf1 = *(const uint4*)(Ss[1] + scoff);
    pf2 = *(const uint4*)(Ss[2] + scoff);
    if (tid < 128) pfm = Mw[moff];
    *(uint4*)&bt[0][scol][spart * 8] = pf0;
    *(uint4*)&bt[1][scol][spart * 8] = pf1;
    *(uint4*)&bt[2][scol][spart * 8] = pf2;
    if (tid < 128) msk[tid] = pfm;
    __syncthreads();

    for (int t = 0; t < NN / 32; ++t) {
        // issue next tile's global loads (no use until after the barrier)
        if (t < NN / 32 - 1) {
            const size_t j = (size_t)(t + 1) * 32;
            pf0 = *(const uint4*)(Ss[0] + scoff + j);
            pf1 = *(const uint4*)(Ss[1] + scoff + j);
            pf2 = *(const uint4*)(Ss[2] + scoff + j);
            if (tid < 128) pfm = Mw[moff + (t + 1)];
        }
        // compute current tile from LDS
        bf16x8 afr[4];
        #pragma unroll
        for (int mt = 0; mt < 4; ++mt) {
            uint w = msk[wrow * 64 + mt * 16 + ln];
            uint byte = (w >> (quad * 8)) & 0xFFu;
            union { uint u[4]; bf16x8 v; } cv;
            #pragma unroll
            for (int p = 0; p < 4; ++p)
                cv.u[p] = (((byte >> (2 * p)) & 1u) ? 0x3F80u : 0u) |
                          (((byte >> (2 * p + 1)) & 1u) ? 0x3F800000u : 0u);
            afr[mt] = cv.v;
        }
        #pragma unroll
        for (int nt = 0; nt < 2; ++nt) {
            int n = wcol * 32 + nt * 16 + ln;
            bf16x8 bh = *(const bf16x8*)&bt[0][n][quad * 8];
            bf16x8 bm = *(const bf16x8*)&bt[1][n][quad * 8];
            bf16x8 bl = *(const bf16x8*)&bt[2][n][quad * 8];
            #pragma unroll
            for (int mt = 0; mt < 4; ++mt) {
                f32x4 a = acc[mt][nt];
                a = __builtin_amdgcn_mfma_f32_16x16x32_bf16(afr[mt], bh, a, 0, 0, 0);
                a = __builtin_amdgcn_mfma_f32_16x16x32_bf16(afr[mt], bm, a, 0, 0, 0);
                a = __builtin_amdgcn_mfma_f32_16x16x32_bf16(afr[mt], bl, a, 0, 0, 0);
                acc[mt][nt] = a;
            }
        }
        __syncthreads();
        // write next tile into LDS (vmcnt wait happens here, overlapped above)
        if (t < NN / 32 - 1) {
            *(uint4*)&bt[0][scol][spart * 8] = pf0;
            *(uint4*)&bt[1][scol][spart * 8] = pf1;
            *(uint4*)&bt[2][scol][spart * 8] = pf2;
            if (tid < 128) msk[tid] = pfm;
        }
        __syncthreads();
    }
    #pragma unroll
    for (int mt = 0; mt < 4; ++mt)
        #pragma unroll
        for (int nt = 0; nt < 2; ++nt)
            #pragma unroll
            for (int r = 0; r < 4; ++r) {
                int row = row0 + wrow * 64 + mt * 16 + quad * 4 + r;
                int col = col0 + wcol * 32 + nt * 16 + ln;
                size_t idx = (size_t)row * DD + col;
                X[idx] = X[idx] + acc[mt][nt][r];
            }
}

// ---------------------------------------------------------------------------
// X = relu(bn(G)) @ W + bias;  acc (+)= X.  (proven)
// ---------------------------------------------------------------------------
__global__ __launch_bounds__(256, 4)
void gemm_bnrelu(const float* __restrict__ G, Ptrs4 Wp, Ptrs4 bp, Ptrs4 gbp,
                 const float* __restrict__ bns, const float* __restrict__ bnq,
                 float* __restrict__ Xout, float* __restrict__ accb, int first)
{
    const int b = blockIdx.z;
    const float* Wb = sel(Wp, b);
    const float* bb = sel(bp, b);
    const float* gb = sel(gbp, b);
    const float* Gb = G + (size_t)b * NN * DD;
    float* O = Xout + (size_t)b * NN * DD;
    float* Ab = accb + (size_t)b * NN * DD;
    const int row0 = blockIdx.y * 128, col0 = blockIdx.x * 64;
    const int tid = threadIdx.x;
    __shared__ float Asm[16][132];
    __shared__ float Bsm[16][68];
    __shared__ float scs[DD], shs[DD];
    {
        float mu = bns[b * DD + tid] * (1.0f / NN);
        float ms = bnq[b * DD + tid] * (1.0f / NN);
        float var = ms - mu * mu;
        float sc = gb[tid] / sqrtf(var + 1e-5f);
        scs[tid] = sc;
        shs[tid] = gb[DD + tid] - mu * sc;
    }
    __syncthreads();
    const int tr = (tid >> 4) << 3, tc = (tid & 15) << 2;
    const int m = tid & 127, kk = (tid >> 7) << 3;
    float acc[8][4] = {};
    for (int k0 = 0; k0 < DD; k0 += 16) {
        {
            const float* s1 = Gb + (size_t)(row0 + m) * DD + k0 + kk;
            float4 v0 = *(const float4*)s1, v1 = *(const float4*)(s1 + 4);
            float vv[8] = {v0.x, v0.y, v0.z, v0.w, v1.x, v1.y, v1.z, v1.w};
            #pragma unroll
            for (int i = 0; i < 8; ++i) {
                float v = fmaf(vv[i], scs[k0 + kk + i], shs[k0 + kk + i]);
                Asm[kk + i][m] = v > 0.f ? v : 0.f;
            }
        }
        {
            const int k = tid >> 4, n = (tid & 15) << 2;
            *(float4*)&Bsm[k][n] = *(const float4*)(Wb + (size_t)(k0 + k) * DD + col0 + n);
        }
        __syncthreads();
        #pragma unroll
        for (int k = 0; k < 16; ++k) {
            float a[8], bv[4];
            *(float4*)&a[0] = *(const float4*)&Asm[k][tr];
            *(float4*)&a[4] = *(const float4*)&Asm[k][tr + 4];
            *(float4*)&bv[0] = *(const float4*)&Bsm[k][tc];
            #pragma unroll
            for (int i = 0; i < 8; ++i)
                #pragma unroll
                for (int j = 0; j < 4; ++j)
                    acc[i][j] = fmaf(a[i], bv[j], acc[i][j]);
        }
        __syncthreads();
    }
    float bias4[4];
    *(float4*)bias4 = *(const float4*)(bb + col0 + tc);
    #pragma unroll
    for (int i = 0; i < 8; ++i) {
        size_t idx = (size_t)(row0 + tr + i) * DD + col0 + tc;
        float4 o;
        o.x = acc[i][0] + bias4[0]; o.y = acc[i][1] + bias4[1];
        o.z = acc[i][2] + bias4[2]; o.w = acc[i][3] + bias4[3];
        *(float4*)(O + idx) = o;
        if (first) {
            *(float4*)(Ab + idx) = o;
        } else {
            float4 p = *(const float4*)(Ab + idx);
            p.x += o.x; p.y += o.y; p.z += o.z; p.w += o.w;
            *(float4*)(Ab + idx) = p;
        }
    }
}

__global__ __launch_bounds__(256)
void mse_partial(const float* __restrict__ accb, double* __restrict__ msep)
{
    const int pair = blockIdx.x;
    const float* A_ = accb + (size_t)pair * NN * DD;
    const float* B_ = accb + (size_t)3 * NN * DD;
    const size_t total = (size_t)NN * DD;
    double s = 0.0;
    for (size_t i = (size_t)blockIdx.y * blockDim.x + threadIdx.x; i < total;
         i += (size_t)gridDim.y * blockDim.x) {
        float d = A_[i] - B_[i];
        s += (double)d * (double)d;
    }
    __shared__ double red[256];
    red[threadIdx.x] = s;
    __syncthreads();
    for (int st = 128; st > 0; st >>= 1) {
        if (threadIdx.x < st) red[threadIdx.x] += red[threadIdx.x + st];
        __syncthreads();
    }
    if (threadIdx.x == 0) atomicAdd(&msep[pair], red[0]);
}

__global__ void mse_final(const double* __restrict__ msep, float* __restrict__ out)
{
    int i = threadIdx.x;
    if (i < 3) out[i] = (float)(msep[i] / ((double)NN * DD) / 9.0);
}

static inline Ptrs4 mk4(const float* a, const float* b, const float* c, const float* d) {
    Ptrs4 p; p.p0 = a; p.p1 = b; p.p2 = c; p.p3 = d; return p;
}

extern "C" void kernel_launch(void* const* d_in, const int* in_sizes, int n_in,
                              void* d_out, int out_size, void* d_ws, size_t ws_size,
                              hipStream_t stream)
{
    (void)in_sizes; (void)n_in; (void)out_size;
    const float* adjW[3]  = {(const float*)d_in[4],  (const float*)d_in[9],  (const float*)d_in[14]};
    const float* adjb[3]  = {(const float*)d_in[5],  (const float*)d_in[10], (const float*)d_in[15]};
    const float* mlpW[3]  = {(const float*)d_in[6],  (const float*)d_in[11], (const float*)d_in[16]};
    const float* mlpb[3]  = {(const float*)d_in[7],  (const float*)d_in[12], (const float*)d_in[17]};
    const float* mlpbn[3] = {(const float*)d_in[8],  (const float*)d_in[13], (const float*)d_in[18]};

    char* ws = (char*)d_ws;
    double* msep  = (double*)ws;                 // [3]
    float* colsum = (float*)(ws + 64);           // [3][4][256]
    float* bnsum  = colsum + 3 * 4 * DD;
    float* bnsq   = bnsum  + 3 * 4 * DD;
    float* tvals  = bnsq   + 3 * 4 * DD;         // [4]
    const size_t tensN = (size_t)4 * NN * DD;             // elements per fp32 tensor set
    const size_t HS_BYTES = (size_t)4 * 3 * DD * NN * 2;  // 25.17 MB split region
    const size_t MASK_BYTES = (size_t)4 * NN * (NN / 8);  // 8.39 MB

    float* Xbuf = (float*)(ws + 65536);
    float* Abuf = Xbuf + tensN;

    // fast path needs: 64K + Xbuf + Abuf + Hs-region + accb + mask
    const size_t need_fast = 65536 + 2 * tensN * 4 + HS_BYTES + tensN * 4 + MASK_BYTES;
    const bool fast = ws_size >= need_fast;

    float* Bbuf = nullptr; float* accb; uint8_t* mask;
    ushort_t *Sh, *Sm, *Sl, *HsG = nullptr;
    if (fast) {
        // Hs region (gemm1->adj) time-shares with Sl (tsplit->masked): disjoint lifetimes
        char* hr = (char*)(Abuf + tensN);
        HsG  = (ushort_t*)hr;
        Sl   = (ushort_t*)hr;
        accb = (float*)(hr + HS_BYTES);
        mask = (uint8_t*)(accb + tensN);
    } else {
        // proven 75.5 MB layout, unchanged behavior
        Bbuf = Abuf + tensN;
        accb = Bbuf + tensN;
        mask = (uint8_t*)(accb + tensN);
        Sl   = (ushort_t*)Bbuf;
    }
    Sh = (ushort_t*)Abuf;
    Sm = Sh + tensN;

    hipMemsetAsync(ws, 0, 64 + 3 * 3 * 4 * DD * sizeof(float), stream);
    for (int b = 0; b < 4; ++b)
        hipMemcpyAsync(Xbuf + (size_t)b * NN * DD, d_in[b], (size_t)NN * DD * sizeof(float),
                       hipMemcpyDeviceToDevice, stream);

    dim3 gS(4, 32, 4);      // fp32 GEMMs / masked_mfma
    dim3 gA(528, 1, 4);     // adj tiles, compact upper-tri
    dim3 gT(64, 4, 4);      // tsplit_x
    dim3 blk(256);

    for (int l = 0; l < NL; ++l) {
        float* cs_l = colsum + l * 4 * DD;
        float* bs_l = bnsum + l * 4 * DD;
        float* bq_l = bnsq  + l * 4 * DD;
        #define MK(arr, off) mk4(arr[0] + (off), arr[1] + (off), arr[2] + (off), arr[1] + (off))
        // h1 = elu(X @ aW0 + ab0)  -> Abuf
        gemm_small<0><<<gS, blk, 0, stream>>>(Xbuf, MK(adjW, 0), MK(adjb, 0), Abuf,
                                              nullptr, nullptr, (ushort_t*)nullptr);
        if (fast) {
            // h2 = elu(h1 @ aW1 + ab1) -> bf16 3-split Hs + colsum (no fp32 h2)
            gemm_small<3><<<gS, blk, 0, stream>>>(Abuf, MK(adjW, (size_t)DD * DD), MK(adjb, DD),
                                                  nullptr, cs_l, nullptr, HsG);
            thresh_k<<<4, blk, 0, stream>>>(cs_l, tvals);
            adj_mfma_v2<<<gA, blk, 0, stream>>>(HsG, tvals, mask);
        } else {
            gemm_small<1><<<gS, blk, 0, stream>>>(Abuf, MK(adjW, (size_t)DD * DD), MK(adjb, DD),
                                                  Bbuf, cs_l, nullptr, (ushort_t*)nullptr);
            thresh_k<<<4, blk, 0, stream>>>(cs_l, tvals);
            adj_mfma_s<<<gA, blk, 0, stream>>>(Bbuf, tvals, mask);
        }
        // splits of X^T (h1 dead; Hs dead after adj) -> Sh,Sm (Abuf), Sl
        tsplit_x<<<gT, blk, 0, stream>>>(Xbuf, Sh, Sm, Sl);
        // X = X + M @ X   (in-place Xbuf)
        masked_mfma<<<gS, blk, 0, stream>>>(Xbuf, Sh, Sm, Sl, mask);
        const size_t w0 = (size_t)l * 2 * DD * DD, b0 = (size_t)l * 2 * DD;
        // g = X' @ mW0 + mb0 + BN stats  -> Abuf (splits dead)
        gemm_small<2><<<gS, blk, 0, stream>>>(Xbuf, MK(mlpW, w0), MK(mlpb, b0), Abuf,
                                              bs_l, bq_l, (ushort_t*)nullptr);
        // X = relu(bn(g)) @ mW1 + mb1;  acc (+)= X  -> Xbuf
        gemm_bnrelu<<<gS, blk, 0, stream>>>(Abuf, MK(mlpW, w0 + (size_t)DD * DD), MK(mlpb, b0 + DD),
                                            MK(mlpbn, b0), bs_l, bq_l, Xbuf, accb, (l == 0) ? 1 : 0);
        #undef MK
    }
    mse_partial<<<dim3(3, 64), blk, 0, stream>>>(accb, msep);
    mse_final<<<1, 64, 0, stream>>>(msep, (float*)d_out);
}

// Round 3
// 1207.997 us; speedup vs baseline: 1.2586x; 1.2586x over previous
//
#include <hip/hip_runtime.h>
#include <hip/hip_bf16.h>
#include <stdint.h>

#define NN 4096
#define DD 256
#define NL 3
typedef unsigned int uint;
typedef unsigned short ushort_t;

typedef float f32x4 __attribute__((ext_vector_type(4)));
typedef short bf16x8 __attribute__((ext_vector_type(8)));

struct Ptrs4 { const float* p0; const float* p1; const float* p2; const float* p3; };
__device__ __forceinline__ const float* sel(const Ptrs4& p, int b) {
    return b == 0 ? p.p0 : b == 1 ? p.p1 : b == 2 ? p.p2 : p.p3;
}

// packed bf16 pair (RNE), low half = a, high half = b
__device__ __forceinline__ uint pkbf2(float a, float b) {
    __hip_bfloat162 t = __float22bfloat162_rn(float2{a, b});
    union { __hip_bfloat162 h; uint u; } c; c.h = t; return c.u;
}
// exact 3-way split of a pair: x = h + m + l + r, |r| <= ~2^-27 |x|
__device__ __forceinline__ void split3_pk(float a, float b, uint& h, uint& m, uint& l) {
    h = pkbf2(a, b);
    float ha = __uint_as_float(h << 16), hb = __uint_as_float(h & 0xFFFF0000u);
    float ra = a - ha, rb = b - hb;
    m = pkbf2(ra, rb);
    float ma = __uint_as_float(m << 16), mb = __uint_as_float(m & 0xFFFF0000u);
    l = pkbf2(ra - ma, rb - mb);
}

// async global->LDS; LDS dest = wave-uniform base + lane*size
typedef __attribute__((address_space(3))) uint lds_u32;
typedef __attribute__((address_space(1))) const uint glb_u32;
__device__ __forceinline__ void gload16(void* l, const void* g) {
    __builtin_amdgcn_global_load_lds((glb_u32*)g, (lds_u32*)l, 16, 0, 0);
}
__device__ __forceinline__ void gload4(void* l, const void* g) {
    __builtin_amdgcn_global_load_lds((glb_u32*)g, (lds_u32*)l, 4, 0, 0);
}

// ---------------------------------------------------------------------------
// fp32 GEMM (proven): Out = act(X @ W + b).
// MODE 0: elu; MODE 1: elu + colsum (fp32 out, fallback path);
// MODE 2: linear + BN stats;
// MODE 3: elu + colsum, output = bf16 3-split in Hs[lvl][k/8][n][8] layout
//         (no fp32 out) -- feeds adj_mfma_v2 directly.
// ---------------------------------------------------------------------------
template<int MODE>
__global__ __launch_bounds__(256, 4)
void gemm_small(const float* __restrict__ Xin, Ptrs4 Wp, Ptrs4 bp,
                float* __restrict__ Out, float* __restrict__ cs, float* __restrict__ csq,
                ushort_t* __restrict__ Hso)
{
    const int b = blockIdx.z;
    const float* Wb = sel(Wp, b);
    const float* bb = sel(bp, b);
    const float* X = Xin + (size_t)b * NN * DD;
    float* O = Out + (size_t)b * NN * DD;
    ushort_t* HsO = Hso + (size_t)b * 3 * (size_t)DD * NN;
    const int row0 = blockIdx.y * 128, col0 = blockIdx.x * 64;
    const int tid = threadIdx.x;
    __shared__ float Asm[16][132];
    __shared__ float Bsm[16][68];
    const int tr = (tid >> 4) << 3, tc = (tid & 15) << 2;
    const int m = tid & 127, kk = (tid >> 7) << 3;
    float acc[8][4] = {};
    for (int k0 = 0; k0 < DD; k0 += 16) {
        {
            const float* s1 = X + (size_t)(row0 + m) * DD + k0 + kk;
            float4 v0 = *(const float4*)s1, v1 = *(const float4*)(s1 + 4);
            Asm[kk+0][m]=v0.x; Asm[kk+1][m]=v0.y; Asm[kk+2][m]=v0.z; Asm[kk+3][m]=v0.w;
            Asm[kk+4][m]=v1.x; Asm[kk+5][m]=v1.y; Asm[kk+6][m]=v1.z; Asm[kk+7][m]=v1.w;
        }
        {
            const int k = tid >> 4, n = (tid & 15) << 2;
            *(float4*)&Bsm[k][n] = *(const float4*)(Wb + (size_t)(k0 + k) * DD + col0 + n);
        }
        __syncthreads();
        #pragma unroll
        for (int k = 0; k < 16; ++k) {
            float a[8], bv[4];
            *(float4*)&a[0] = *(const float4*)&Asm[k][tr];
            *(float4*)&a[4] = *(const float4*)&Asm[k][tr + 4];
            *(float4*)&bv[0] = *(const float4*)&Bsm[k][tc];
            #pragma unroll
            for (int i = 0; i < 8; ++i)
                #pragma unroll
                for (int j = 0; j < 4; ++j)
                    acc[i][j] = fmaf(a[i], bv[j], acc[i][j]);
        }
        __syncthreads();
    }
    float bias4[4];
    *(float4*)bias4 = *(const float4*)(bb + col0 + tc);
    float s4[4] = {0.f,0.f,0.f,0.f}, q4[4] = {0.f,0.f,0.f,0.f};
    // MODE 3 split-store geometry: d = col0+tc (mult of 4), layout [lvl][d>>3][n][8]
    const int dph = col0 + tc;
    const size_t sb3 = (size_t)(dph >> 3) * (NN * 8) + (dph & 4);
    #pragma unroll
    for (int i = 0; i < 8; ++i) {
        float ov[4];
        #pragma unroll
        for (int j = 0; j < 4; ++j) {
            float v = acc[i][j] + bias4[j];
            if (MODE == 0 || MODE == 1 || MODE == 3) v = (v > 0.f) ? v : (expf(v) - 1.f);
            ov[j] = v;
            if (MODE == 1 || MODE == 3) s4[j] += v;
            if (MODE == 2) { s4[j] += v; q4[j] += v * v; }
        }
        if (MODE == 3) {
            uint2 vh, vm, vl;
            split3_pk(ov[0], ov[1], vh.x, vm.x, vl.x);
            split3_pk(ov[2], ov[3], vh.y, vm.y, vl.y);
            size_t off = sb3 + (size_t)(row0 + tr + i) * 8;
            *(uint2*)(HsO + off) = vh;
            *(uint2*)(HsO + (size_t)DD * NN + off) = vm;
            *(uint2*)(HsO + (size_t)2 * DD * NN + off) = vl;
        } else {
            float4 o; o.x = ov[0]; o.y = ov[1]; o.z = ov[2]; o.w = ov[3];
            *(float4*)(O + (size_t)(row0 + tr + i) * DD + col0 + tc) = o;
        }
    }
    if (MODE == 1 || MODE == 2 || MODE == 3) {
        __syncthreads();
        const int rg = tid >> 4;
        #pragma unroll
        for (int j = 0; j < 4; ++j) {
            Asm[rg][tc + j] = s4[j];
            if (MODE == 2) Bsm[rg][tc + j] = q4[j];
        }
        __syncthreads();
        if (tid < 64) {
            float s = 0.f, q = 0.f;
            #pragma unroll
            for (int r = 0; r < 16; ++r) { s += Asm[r][tid]; if (MODE == 2) q += Bsm[r][tid]; }
            atomicAdd(&cs[b * DD + col0 + tid], s);
            if (MODE == 2) atomicAdd(&csq[b * DD + col0 + tid], q);
        }
    }
}

// threshold per branch: t = ||colsum||^2 / N^2
__global__ void thresh_k(const float* __restrict__ cs, float* __restrict__ tvals)
{
    const int b = blockIdx.x, t = threadIdx.x;
    __shared__ float red[256];
    float v = cs[b * DD + t];
    red[t] = v * v;
    __syncthreads();
    for (int s = 128; s > 0; s >>= 1) { if (t < s) red[t] += red[t + s]; __syncthreads(); }
    if (t == 0) tvals[b] = red[0] * (1.0f / 16777216.0f);
}

// ---------------------------------------------------------------------------
// transpose + exact 3-split: X[b][n][d] fp32 -> S{h,m,l}[b][d][j=n] bf16.
// j-contiguous layout = MFMA k-order for masked_mfma's B operand.  (proven)
// ---------------------------------------------------------------------------
__global__ __launch_bounds__(256)
void tsplit_x(const float* __restrict__ Xin, ushort_t* __restrict__ Sh,
              ushort_t* __restrict__ Sm, ushort_t* __restrict__ Sl)
{
    const int b = blockIdx.z;
    const int n0 = blockIdx.x * 64, d0 = blockIdx.y * 64;
    const float* X = Xin + (size_t)b * NN * DD;
    __shared__ float ls[64][65];
    const int tid = threadIdx.x;
    #pragma unroll
    for (int i = 0; i < 4; ++i) {
        int u = (i << 8) + tid;
        int r = u >> 4, c4 = (u & 15) << 2;   // r = n-row, c4 = d offset
        float4 v = *(const float4*)(X + (size_t)(n0 + r) * DD + d0 + c4);
        ls[r][c4] = v.x; ls[r][c4+1] = v.y; ls[r][c4+2] = v.z; ls[r][c4+3] = v.w;
    }
    __syncthreads();
    const int d = tid >> 2, seg = (tid & 3) << 4;   // 16 n-values per thread
    uint ph[8], pm[8], pl[8];
    #pragma unroll
    for (int jj = 0; jj < 8; ++jj) {
        float a = ls[seg + 2 * jj][d];
        float c = ls[seg + 2 * jj + 1][d];
        split3_pk(a, c, ph[jj], pm[jj], pl[jj]);
    }
    size_t idx = ((size_t)(b * DD + d0 + d)) * NN + n0 + seg;   // ushort units
    *(uint4*)(Sh + idx)     = *(uint4*)&ph[0];
    *(uint4*)(Sh + idx + 8) = *(uint4*)&ph[4];
    *(uint4*)(Sm + idx)     = *(uint4*)&pm[0];
    *(uint4*)(Sm + idx + 8) = *(uint4*)&pm[4];
    *(uint4*)(Sl + idx)     = *(uint4*)&pl[0];
    *(uint4*)(Sl + idx + 8) = *(uint4*)&pl[4];
}

// ---------------------------------------------------------------------------
// adj v1 (fallback, proven): fp32 staging + in-tile split.
// ---------------------------------------------------------------------------
__global__ __launch_bounds__(256, 3)
void adj_mfma_s(const float* __restrict__ H, const float* __restrict__ tvals,
                uint8_t* __restrict__ mask)
{
    int t = blockIdx.x;
    int by = 0, rem = 32;
    while (t >= rem) { t -= rem; rem--; by++; }
    const int bx = by + t;
    const int b = blockIdx.z;
    const int row0 = by * 128, col0 = bx * 128;
    const int tid = threadIdx.x;
    const int wave = tid >> 6, ln = tid & 15, quad = (tid >> 4) & 3;
    const int wrow = wave >> 1, wcol = wave & 1;
    const float* Hb = H + (size_t)b * NN * DD;
    uint8_t* Mb = mask + (size_t)b * NN * (NN / 8);
    __shared__ ushort_t hs[2][3][128][34];   // [side][lvl][row][32k+pad], 51.0 KB

    f32x4 acc[4][4] = {};
    for (int k0 = 0; k0 < DD; k0 += 32) {
        #pragma unroll
        for (int i = 0; i < 8; ++i) {
            int f = (i << 8) + tid;
            int sr = f >> 3;
            int side = sr >> 7, r = sr & 127, part = f & 7;
            int grow = (side ? col0 : row0) + r;
            float4 v = *(const float4*)(Hb + (size_t)grow * DD + k0 + part * 4);
            uint h0, m0, l0, h1, m1, l1;
            split3_pk(v.x, v.y, h0, m0, l0);
            split3_pk(v.z, v.w, h1, m1, l1);
            uint2 ph; ph.x = h0; ph.y = h1;
            uint2 pm; pm.x = m0; pm.y = m1;
            uint2 pl; pl.x = l0; pl.y = l1;
            *(uint2*)&hs[side][0][r][part * 4] = ph;
            *(uint2*)&hs[side][1][r][part * 4] = pm;
            *(uint2*)&hs[side][2][r][part * 4] = pl;
        }
        __syncthreads();
        bf16x8 af[4][3];
        #pragma unroll
        for (int mt = 0; mt < 4; ++mt)
            #pragma unroll
            for (int lvl = 0; lvl < 3; ++lvl)
                af[mt][lvl] = *(const bf16x8*)&hs[0][lvl][wrow * 64 + mt * 16 + ln][quad * 8];
        #pragma unroll
        for (int nt = 0; nt < 4; ++nt) {
            int n = wcol * 64 + nt * 16 + ln;
            bf16x8 bh = *(const bf16x8*)&hs[1][0][n][quad * 8];
            bf16x8 bm = *(const bf16x8*)&hs[1][1][n][quad * 8];
            bf16x8 bl = *(const bf16x8*)&hs[1][2][n][quad * 8];
            #pragma unroll
            for (int mt = 0; mt < 4; ++mt) {
                f32x4 a = acc[mt][nt];
                a = __builtin_amdgcn_mfma_f32_16x16x32_bf16(af[mt][0], bh, a, 0, 0, 0);
                a = __builtin_amdgcn_mfma_f32_16x16x32_bf16(af[mt][0], bm, a, 0, 0, 0);
                a = __builtin_amdgcn_mfma_f32_16x16x32_bf16(af[mt][1], bh, a, 0, 0, 0);
                a = __builtin_amdgcn_mfma_f32_16x16x32_bf16(af[mt][0], bl, a, 0, 0, 0);
                a = __builtin_amdgcn_mfma_f32_16x16x32_bf16(af[mt][2], bh, a, 0, 0, 0);
                a = __builtin_amdgcn_mfma_f32_16x16x32_bf16(af[mt][1], bm, a, 0, 0, 0);
                acc[mt][nt] = a;
            }
        }
        __syncthreads();
    }
    const float t2 = tvals[b];
    #pragma unroll
    for (int mt = 0; mt < 4; ++mt)
        #pragma unroll
        for (int nt = 0; nt < 4; ++nt) {
            bool p0 = acc[mt][nt][0] > t2, p1 = acc[mt][nt][1] > t2;
            bool p2 = acc[mt][nt][2] > t2, p3 = acc[mt][nt][3] > t2;
            unsigned long long bal[4];
            bal[0] = __ballot(p0); bal[1] = __ballot(p1);
            bal[2] = __ballot(p2); bal[3] = __ballot(p3);
            if ((tid & 63) < 16) {
                int q = ln >> 2, rsel = ln & 3;
                unsigned long long bv = rsel == 0 ? bal[0] : rsel == 1 ? bal[1]
                                       : rsel == 2 ? bal[2] : bal[3];
                ushort_t u16 = (ushort_t)((bv >> (q * 16)) & 0xFFFFull);
                int row = row0 + wrow * 64 + mt * 16 + ln;
                int colb = (col0 + wcol * 64 + nt * 16) >> 3;
                *(ushort_t*)(Mb + (size_t)row * (NN / 8) + colb) = u16;
            }
            uint nib = (p0 ? 1u : 0u) | (p1 ? 2u : 0u) | (p2 ? 4u : 0u) | (p3 ? 8u : 0u);
            uint other = (uint)__shfl_xor((int)nib, 16);
            if ((quad & 1) == 0) {
                uint byt = nib | (other << 4);
                int rowm = col0 + wcol * 64 + nt * 16 + ln;
                int colbm = ((row0 + wrow * 64 + mt * 16) >> 3) + (quad >> 1);
                Mb[(size_t)rowm * (NN / 8) + colbm] = (uint8_t)byt;
            }
        }
}

// ---------------------------------------------------------------------------
// adj v2 (fast path): pure bf16 MFMA from precomputed splits. (proven R0)
// ---------------------------------------------------------------------------
__global__ __launch_bounds__(256, 3)
void adj_mfma_v2(const ushort_t* __restrict__ Hs, const float* __restrict__ tvals,
                 uint8_t* __restrict__ mask)
{
    int t = blockIdx.x;
    int by = 0, rem = 32;
    while (t >= rem) { t -= rem; rem--; by++; }
    const int bx = by + t;
    const int b = blockIdx.z;
    const int row0 = by * 128, col0 = bx * 128;
    const int tid = threadIdx.x;
    const int wave = tid >> 6, ln = tid & 15, quad = (tid >> 4) & 3;
    const int wrow = wave >> 1, wcol = wave & 1;
    const ushort_t* Hb = Hs + (size_t)b * 3 * (size_t)DD * NN;
    uint8_t* Mb = mask + (size_t)b * NN * (NN / 8);
    __shared__ ushort_t hs2[6][4][128][8];   // 48 KB, linear (DMA-friendly)

    const int grow = tid & 127;
    const int qb = tid >> 7;                  // 0/1
    const size_t var0 = (size_t)qb * (NN * 8) + (size_t)(row0 + grow) * 8;
    const size_t var1 = (size_t)qb * (NN * 8) + (size_t)(col0 + grow) * 8;

    f32x4 acc[4][4] = {};
    for (int kb0 = 0; kb0 < DD / 8; kb0 += 4) {     // 32 k per iter
        #pragma unroll
        for (int c = 0; c < 12; ++c) {
            const int sl = c >> 1, part = c & 1;    // sl = side*3+lvl
            const int side = sl / 3, lvl = sl % 3;
            const ushort_t* g = Hb + (size_t)lvl * DD * NN
                                   + (size_t)(kb0 + part * 2) * (NN * 8)
                                   + (side ? var1 : var0);
            char* l = (char*)&hs2[0][0][0][0] + (((sl * 8 + part * 4 + wave)) << 10);
            gload16(l, g);
        }
        __syncthreads();
        bf16x8 af[4][3];
        #pragma unroll
        for (int mt = 0; mt < 4; ++mt)
            #pragma unroll
            for (int lvl = 0; lvl < 3; ++lvl)
                af[mt][lvl] = *(const bf16x8*)&hs2[lvl][quad][wrow * 64 + mt * 16 + ln][0];
        #pragma unroll
        for (int nt = 0; nt < 4; ++nt) {
            const int n = wcol * 64 + nt * 16 + ln;
            bf16x8 bh = *(const bf16x8*)&hs2[3][quad][n][0];
            bf16x8 bm = *(const bf16x8*)&hs2[4][quad][n][0];
            bf16x8 bl = *(const bf16x8*)&hs2[5][quad][n][0];
            #pragma unroll
            for (int mt = 0; mt < 4; ++mt) {
                f32x4 a = acc[mt][nt];
                a = __builtin_amdgcn_mfma_f32_16x16x32_bf16(af[mt][0], bh, a, 0, 0, 0);
                a = __builtin_amdgcn_mfma_f32_16x16x32_bf16(af[mt][0], bm, a, 0, 0, 0);
                a = __builtin_amdgcn_mfma_f32_16x16x32_bf16(af[mt][1], bh, a, 0, 0, 0);
                a = __builtin_amdgcn_mfma_f32_16x16x32_bf16(af[mt][0], bl, a, 0, 0, 0);
                a = __builtin_amdgcn_mfma_f32_16x16x32_bf16(af[mt][2], bh, a, 0, 0, 0);
                a = __builtin_amdgcn_mfma_f32_16x16x32_bf16(af[mt][1], bm, a, 0, 0, 0);
                acc[mt][nt] = a;
            }
        }
        __syncthreads();
    }
    const float t2 = tvals[b];
    #pragma unroll
    for (int mt = 0; mt < 4; ++mt)
        #pragma unroll
        for (int nt = 0; nt < 4; ++nt) {
            bool p0 = acc[mt][nt][0] > t2, p1 = acc[mt][nt][1] > t2;
            bool p2 = acc[mt][nt][2] > t2, p3 = acc[mt][nt][3] > t2;
            unsigned long long bal[4];
            bal[0] = __ballot(p0); bal[1] = __ballot(p1);
            bal[2] = __ballot(p2); bal[3] = __ballot(p3);
            if ((tid & 63) < 16) {
                int q = ln >> 2, rsel = ln & 3;
                unsigned long long bv = rsel == 0 ? bal[0] : rsel == 1 ? bal[1]
                                       : rsel == 2 ? bal[2] : bal[3];
                ushort_t u16 = (ushort_t)((bv >> (q * 16)) & 0xFFFFull);
                int row = row0 + wrow * 64 + mt * 16 + ln;
                int colb = (col0 + wcol * 64 + nt * 16) >> 3;
                *(ushort_t*)(Mb + (size_t)row * (NN / 8) + colb) = u16;
            }
            uint nib = (p0 ? 1u : 0u) | (p1 ? 2u : 0u) | (p2 ? 4u : 0u) | (p3 ? 8u : 0u);
            uint other = (uint)__shfl_xor((int)nib, 16);
            if ((quad & 1) == 0) {
                uint byt = nib | (other << 4);
                int rowm = col0 + wcol * 64 + nt * 16 + ln;
                int colbm = ((row0 + wrow * 64 + mt * 16) >> 3) + (quad >> 1);
                Mb[(size_t)rowm * (NN / 8) + colbm] = (uint8_t)byt;
            }
        }
}

// ---------------------------------------------------------------------------
// X' = X + M @ X via MFMA, IN-PLACE into X.
// R12: double-buffered global_load_lds pipeline (no staging regs), 64-j
// K-tile (2 k-steps per barrier), XOR-swizzled linear LDS: source seg
// q' = s ^ ((c>>1)&3), same XOR on ds_read -> 2-way (free) bank access.
// Accumulation order identical to proven version => bit-exact.
// ---------------------------------------------------------------------------
__global__ __launch_bounds__(256)
void masked_mfma(float* __restrict__ Xio, const ushort_t* __restrict__ Sh,
                 const ushort_t* __restrict__ Sm, const ushort_t* __restrict__ Sl,
                 const uint8_t* __restrict__ mask)
{
    const int b = blockIdx.z;
    const int row0 = blockIdx.y * 128, col0 = blockIdx.x * 64;
    const int tid = threadIdx.x;
    const int wave = tid >> 6, ln = tid & 15, quad = (tid >> 4) & 3;
    const int wrow = wave >> 1, wcol = wave & 1;
    float* X = Xio + (size_t)b * NN * DD;
    const size_t sb = (size_t)b * DD * NN;
    const ushort_t* Ss[3] = { Sh + sb, Sm + sb, Sl + sb };
    const uint* Mw = (const uint*)(mask + (size_t)b * NN * (NN / 8));
    __shared__ ushort_t bt2[2][3][2][64][32];   // [buf][lvl][khalf][col][32j], 48 KB
    __shared__ uint msk2[2][2][128];            // [buf][khalf][row], 2 KB

    // staging geometry: thread covers col c = tid>>2, physical 16B slot s = tid&3,
    // logical j-seg q' = s ^ ((c>>1)&3)  (inverse swizzle on the global source)
    const int c = tid >> 2;
    const int qp = (tid & 3) ^ ((tid >> 3) & 3);
    const size_t goff = (size_t)(col0 + c) * NN + (size_t)qp * 8;  // + j
    const size_t mrow = (size_t)(row0 + (tid & 127)) * 128;        // uint units

    f32x4 acc[4][2] = {};

    // ---- stage K-tile t into buffer buf (6x gload16 + 2x gload4) ----
    #define STAGE(buf, t)                                                         \
        {                                                                         \
            const size_t j_ = (size_t)(t) * 64;                                   \
            _Pragma("unroll")                                                     \
            for (int lvl = 0; lvl < 3; ++lvl) {                                   \
                gload16((char*)&bt2[buf][lvl][0][0][0] + (wave << 10),            \
                        Ss[lvl] + goff + j_);                                     \
                gload16((char*)&bt2[buf][lvl][1][0][0] + (wave << 10),            \
                        Ss[lvl] + goff + j_ + 32);                                \
            }                                                                     \
            if (tid < 128) {                                                      \
                gload4((char*)&msk2[buf][0][0] + (wave << 8), Mw + mrow + 2*(t)); \
                gload4((char*)&msk2[buf][1][0] + (wave << 8), Mw + mrow + 2*(t)+1);\
            }                                                                     \
        }

    STAGE(0, 0);
    __syncthreads();   // drains vmcnt before barrier -> tile 0 ready

    for (int t = 0; t < NN / 64; ++t) {
        const int cur = t & 1;
        if (t < NN / 64 - 1) STAGE(cur ^ 1, t + 1);   // in-flight across this tile
        #pragma unroll
        for (int kk = 0; kk < 2; ++kk) {
            bf16x8 afr[4];
            #pragma unroll
            for (int mt = 0; mt < 4; ++mt) {
                uint w = msk2[cur][kk][wrow * 64 + mt * 16 + ln];
                uint byte = (w >> (quad * 8)) & 0xFFu;
                union { uint u[4]; bf16x8 v; } cv;
                #pragma unroll
                for (int p = 0; p < 4; ++p)
                    cv.u[p] = (((byte >> (2 * p)) & 1u) ? 0x3F80u : 0u) |
                              (((byte >> (2 * p + 1)) & 1u) ? 0x3F800000u : 0u);
                afr[mt] = cv.v;
            }
            #pragma unroll
            for (int nt = 0; nt < 2; ++nt) {
                const int n = wcol * 32 + nt * 16 + ln;
                const int slot = (quad ^ ((n >> 1) & 3)) * 8;   // read-side XOR
                bf16x8 bh = *(const bf16x8*)&bt2[cur][0][kk][n][slot];
                bf16x8 bm = *(const bf16x8*)&bt2[cur][1][kk][n][slot];
                bf16x8 bl = *(const bf16x8*)&bt2[cur][2][kk][n][slot];
                #pragma unroll
                for (int mt = 0; mt < 4; ++mt) {
                    f32x4 a = acc[mt][nt];
                    a = __builtin_amdgcn_mfma_f32_16x16x32_bf16(afr[mt], bh, a, 0, 0, 0);
                    a = __builtin_amdgcn_mfma_f32_16x16x32_bf16(afr[mt], bm, a, 0, 0, 0);
                    a = __builtin_amdgcn_mfma_f32_16x16x32_bf16(afr[mt], bl, a, 0, 0, 0);
                    acc[mt][nt] = a;
                }
            }
        }
        __syncthreads();   // single barrier: drains next-tile DMA + read/write order
    }
    #undef STAGE
    #pragma unroll
    for (int mt = 0; mt < 4; ++mt)
        #pragma unroll
        for (int nt = 0; nt < 2; ++nt)
            #pragma unroll
            for (int r = 0; r < 4; ++r) {
                int row = row0 + wrow * 64 + mt * 16 + quad * 4 + r;
                int col = col0 + wcol * 32 + nt * 16 + ln;
                size_t idx = (size_t)row * DD + col;
                X[idx] = X[idx] + acc[mt][nt][r];   // in-place: each idx owned by one thread
            }
}

// ---------------------------------------------------------------------------
// X = relu(bn(G)) @ W + bias;  acc (+)= X.  (proven)
// ---------------------------------------------------------------------------
__global__ __launch_bounds__(256, 4)
void gemm_bnrelu(const float* __restrict__ G, Ptrs4 Wp, Ptrs4 bp, Ptrs4 gbp,
                 const float* __restrict__ bns, const float* __restrict__ bnq,
                 float* __restrict__ Xout, float* __restrict__ accb, int first)
{
    const int b = blockIdx.z;
    const float* Wb = sel(Wp, b);
    const float* bb = sel(bp, b);
    const float* gb = sel(gbp, b);
    const float* Gb = G + (size_t)b * NN * DD;
    float* O = Xout + (size_t)b * NN * DD;
    float* Ab = accb + (size_t)b * NN * DD;
    const int row0 = blockIdx.y * 128, col0 = blockIdx.x * 64;
    const int tid = threadIdx.x;
    __shared__ float Asm[16][132];
    __shared__ float Bsm[16][68];
    __shared__ float scs[DD], shs[DD];
    {
        float mu = bns[b * DD + tid] * (1.0f / NN);
        float ms = bnq[b * DD + tid] * (1.0f / NN);
        float var = ms - mu * mu;
        float sc = gb[tid] / sqrtf(var + 1e-5f);
        scs[tid] = sc;
        shs[tid] = gb[DD + tid] - mu * sc;
    }
    __syncthreads();
    const int tr = (tid >> 4) << 3, tc = (tid & 15) << 2;
    const int m = tid & 127, kk = (tid >> 7) << 3;
    float acc[8][4] = {};
    for (int k0 = 0; k0 < DD; k0 += 16) {
        {
            const float* s1 = Gb + (size_t)(row0 + m) * DD + k0 + kk;
            float4 v0 = *(const float4*)s1, v1 = *(const float4*)(s1 + 4);
            float vv[8] = {v0.x, v0.y, v0.z, v0.w, v1.x, v1.y, v1.z, v1.w};
            #pragma unroll
            for (int i = 0; i < 8; ++i) {
                float v = fmaf(vv[i], scs[k0 + kk + i], shs[k0 + kk + i]);
                Asm[kk + i][m] = v > 0.f ? v : 0.f;
            }
        }
        {
            const int k = tid >> 4, n = (tid & 15) << 2;
            *(float4*)&Bsm[k][n] = *(const float4*)(Wb + (size_t)(k0 + k) * DD + col0 + n);
        }
        __syncthreads();
        #pragma unroll
        for (int k = 0; k < 16; ++k) {
            float a[8], bv[4];
            *(float4*)&a[0] = *(const float4*)&Asm[k][tr];
            *(float4*)&a[4] = *(const float4*)&Asm[k][tr + 4];
            *(float4*)&bv[0] = *(const float4*)&Bsm[k][tc];
            #pragma unroll
            for (int i = 0; i < 8; ++i)
                #pragma unroll
                for (int j = 0; j < 4; ++j)
                    acc[i][j] = fmaf(a[i], bv[j], acc[i][j]);
        }
        __syncthreads();
    }
    float bias4[4];
    *(float4*)bias4 = *(const float4*)(bb + col0 + tc);
    #pragma unroll
    for (int i = 0; i < 8; ++i) {
        size_t idx = (size_t)(row0 + tr + i) * DD + col0 + tc;
        float4 o;
        o.x = acc[i][0] + bias4[0]; o.y = acc[i][1] + bias4[1];
        o.z = acc[i][2] + bias4[2]; o.w = acc[i][3] + bias4[3];
        *(float4*)(O + idx) = o;
        if (first) {
            *(float4*)(Ab + idx) = o;
        } else {
            float4 p = *(const float4*)(Ab + idx);
            p.x += o.x; p.y += o.y; p.z += o.z; p.w += o.w;
            *(float4*)(Ab + idx) = p;
        }
    }
}

__global__ __launch_bounds__(256)
void mse_partial(const float* __restrict__ accb, double* __restrict__ msep)
{
    const int pair = blockIdx.x;
    const float* A_ = accb + (size_t)pair * NN * DD;
    const float* B_ = accb + (size_t)3 * NN * DD;
    const size_t total = (size_t)NN * DD;
    double s = 0.0;
    for (size_t i = (size_t)blockIdx.y * blockDim.x + threadIdx.x; i < total;
         i += (size_t)gridDim.y * blockDim.x) {
        float d = A_[i] - B_[i];
        s += (double)d * (double)d;
    }
    __shared__ double red[256];
    red[threadIdx.x] = s;
    __syncthreads();
    for (int st = 128; st > 0; st >>= 1) {
        if (threadIdx.x < st) red[threadIdx.x] += red[threadIdx.x + st];
        __syncthreads();
    }
    if (threadIdx.x == 0) atomicAdd(&msep[pair], red[0]);
}

__global__ void mse_final(const double* __restrict__ msep, float* __restrict__ out)
{
    int i = threadIdx.x;
    if (i < 3) out[i] = (float)(msep[i] / ((double)NN * DD) / 9.0);
}

static inline Ptrs4 mk4(const float* a, const float* b, const float* c, const float* d) {
    Ptrs4 p; p.p0 = a; p.p1 = b; p.p2 = c; p.p3 = d; return p;
}

extern "C" void kernel_launch(void* const* d_in, const int* in_sizes, int n_in,
                              void* d_out, int out_size, void* d_ws, size_t ws_size,
                              hipStream_t stream)
{
    (void)in_sizes; (void)n_in; (void)out_size;
    const float* adjW[3]  = {(const float*)d_in[4],  (const float*)d_in[9],  (const float*)d_in[14]};
    const float* adjb[3]  = {(const float*)d_in[5],  (const float*)d_in[10], (const float*)d_in[15]};
    const float* mlpW[3]  = {(const float*)d_in[6],  (const float*)d_in[11], (const float*)d_in[16]};
    const float* mlpb[3]  = {(const float*)d_in[7],  (const float*)d_in[12], (const float*)d_in[17]};
    const float* mlpbn[3] = {(const float*)d_in[8],  (const float*)d_in[13], (const float*)d_in[18]};

    char* ws = (char*)d_ws;
    double* msep  = (double*)ws;                 // [3]
    float* colsum = (float*)(ws + 64);           // [3][4][256]
    float* bnsum  = colsum + 3 * 4 * DD;
    float* bnsq   = bnsum  + 3 * 4 * DD;
    float* tvals  = bnsq   + 3 * 4 * DD;         // [4]
    const size_t tensN = (size_t)4 * NN * DD;             // elements per fp32 tensor set
    const size_t HS_BYTES = (size_t)4 * 3 * DD * NN * 2;  // 25.17 MB split region
    const size_t MASK_BYTES = (size_t)4 * NN * (NN / 8);  // 8.39 MB

    float* Xbuf = (float*)(ws + 65536);
    float* Abuf = Xbuf + tensN;

    // fast path needs: 64K + Xbuf + Abuf + Hs-region + accb + mask
    const size_t need_fast = 65536 + 2 * tensN * 4 + HS_BYTES + tensN * 4 + MASK_BYTES;
    const bool fast = ws_size >= need_fast;

    float* Bbuf = nullptr; float* accb; uint8_t* mask;
    ushort_t *Sh, *Sm, *Sl, *HsG = nullptr;
    if (fast) {
        // Hs region (gemm1->adj) time-shares with Sl (tsplit->masked): disjoint lifetimes
        char* hr = (char*)(Abuf + tensN);
        HsG  = (ushort_t*)hr;
        Sl   = (ushort_t*)hr;
        accb = (float*)(hr + HS_BYTES);
        mask = (uint8_t*)(accb + tensN);
    } else {
        // proven 75.5 MB layout, unchanged behavior
        Bbuf = Abuf + tensN;
        accb = Bbuf + tensN;
        mask = (uint8_t*)(accb + tensN);
        Sl   = (ushort_t*)Bbuf;
    }
    Sh = (ushort_t*)Abuf;
    Sm = Sh + tensN;

    hipMemsetAsync(ws, 0, 64 + 3 * 3 * 4 * DD * sizeof(float), stream);
    for (int b = 0; b < 4; ++b)
        hipMemcpyAsync(Xbuf + (size_t)b * NN * DD, d_in[b], (size_t)NN * DD * sizeof(float),
                       hipMemcpyDeviceToDevice, stream);

    dim3 gS(4, 32, 4);      // fp32 GEMMs / masked_mfma
    dim3 gA(528, 1, 4);     // adj tiles, compact upper-tri
    dim3 gT(64, 4, 4);      // tsplit_x
    dim3 blk(256);

    for (int l = 0; l < NL; ++l) {
        float* cs_l = colsum + l * 4 * DD;
        float* bs_l = bnsum + l * 4 * DD;
        float* bq_l = bnsq  + l * 4 * DD;
        #define MK(arr, off) mk4(arr[0] + (off), arr[1] + (off), arr[2] + (off), arr[1] + (off))
        // h1 = elu(X @ aW0 + ab0)  -> Abuf
        gemm_small<0><<<gS, blk, 0, stream>>>(Xbuf, MK(adjW, 0), MK(adjb, 0), Abuf,
                                              nullptr, nullptr, (ushort_t*)nullptr);
        if (fast) {
            // h2 = elu(h1 @ aW1 + ab1) -> bf16 3-split Hs + colsum (no fp32 h2)
            gemm_small<3><<<gS, blk, 0, stream>>>(Abuf, MK(adjW, (size_t)DD * DD), MK(adjb, DD),
                                                  nullptr, cs_l, nullptr, HsG);
            thresh_k<<<4, blk, 0, stream>>>(cs_l, tvals);
            adj_mfma_v2<<<gA, blk, 0, stream>>>(HsG, tvals, mask);
        } else {
            gemm_small<1><<<gS, blk, 0, stream>>>(Abuf, MK(adjW, (size_t)DD * DD), MK(adjb, DD),
                                                  Bbuf, cs_l, nullptr, (ushort_t*)nullptr);
            thresh_k<<<4, blk, 0, stream>>>(cs_l, tvals);
            adj_mfma_s<<<gA, blk, 0, stream>>>(Bbuf, tvals, mask);
        }
        // splits of X^T (h1 dead; Hs dead after adj) -> Sh,Sm (Abuf), Sl
        tsplit_x<<<gT, blk, 0, stream>>>(Xbuf, Sh, Sm, Sl);
        // X = X + M @ X   (in-place Xbuf)
        masked_mfma<<<gS, blk, 0, stream>>>(Xbuf, Sh, Sm, Sl, mask);
        const size_t w0 = (size_t)l * 2 * DD * DD, b0 = (size_t)l * 2 * DD;
        // g = X' @ mW0 + mb0 + BN stats  -> Abuf (splits dead)
        gemm_small<2><<<gS, blk, 0, stream>>>(Xbuf, MK(mlpW, w0), MK(mlpb, b0), Abuf,
                                              bs_l, bq_l, (ushort_t*)nullptr);
        // X = relu(bn(g)) @ mW1 + mb1;  acc (+)= X  -> Xbuf
        gemm_bnrelu<<<gS, blk, 0, stream>>>(Abuf, MK(mlpW, w0 + (size_t)DD * DD), MK(mlpb, b0 + DD),
                                            MK(mlpbn, b0), bs_l, bq_l, Xbuf, accb, (l == 0) ? 1 : 0);
        #undef MK
    }
    mse_partial<<<dim3(3, 64), blk, 0, stream>>>(accb, msep);
    mse_final<<<1, 64, 0, stream>>>(msep, (float*)d_out);
}